// Round 19
// baseline (4714.512 us; speedup 1.0000x reference)
//
#include <hip/hip_runtime.h>

// DualEncoderLSTMDense: dual peephole-LSTM encoders (shared weights) + M-projection + tiny MLP.
// B=256, L=128, E=256, H=512, VOCAB=90000, NUM_NEG=4, forget_bias=2.0.
//
// Round 19: R18's 8-wave quad-split block (2 waves/SIMD, proven: occupancy 12->24.6%)
// + R8/R16's bid mapping rowTile=bid&7, hidTile=bid>>3 (proven: XCD-local row-groups ->
// emb fetched once/XCD/step, streamed W union 4MB=L2; R18's bid>>5 mapping spread groups
// across XCDs -> FETCH 122->793MB, the whole regression). Single-variable vs both parents:
// R18 isolates mapping, R16 isolates occupancy. Quad0 = x-part + h ks0..3 + reduce +
// gates + publish; quad1 = h ks4..15 -> LDS partials. absmax 1.953125e-3 (R18-verified).

typedef unsigned short u16;
typedef unsigned long long u64;
typedef __attribute__((ext_vector_type(8))) short    s16x8;
typedef __attribute__((ext_vector_type(4))) float    f32x4;
typedef __attribute__((ext_vector_type(4))) unsigned u32x4;

#define MFMA(a, b, c) __builtin_amdgcn_mfma_f32_16x16x32_bf16((a), (b), (c), 0, 0, 0)

__device__ __forceinline__ u16 f2bf(float f) {
    union { float f; unsigned u; } v; v.f = f;
    unsigned r = v.u + 0x7FFFu + ((v.u >> 16) & 1u);
    return (u16)(r >> 16);
}
__device__ __forceinline__ float bf2f(u16 h) {
    union { unsigned u; float f; } v; v.u = ((unsigned)h) << 16;
    return v.f;
}
__device__ __forceinline__ float sigm(float x) { return 1.0f / (1.0f + expf(-x)); }

__device__ __forceinline__ void unpack_h(u64 v, s16x8& ah, s16x8& al, int i)
{
    const unsigned w0 = (unsigned)v, w1 = (unsigned)(v >> 32);
    ah[2 * i]     = (short)(u16)w0;
    al[2 * i]     = (short)(u16)(w0 >> 16);
    ah[2 * i + 1] = (short)(u16)w1;
    al[2 * i + 1] = (short)(u16)(w1 >> 16);
}

// ---- transpose fp32 [R][C] -> bf16 hi/lo planes [C][R] ----
__global__ __launch_bounds__(256) void transpose_split(const float* __restrict__ src,
        u16* __restrict__ dhi, u16* __restrict__ dlo, int R, int C)
{
    __shared__ float tile[32][33];
    const int bx = blockIdx.x * 32;
    const int by = blockIdx.y * 32;
    for (int i = threadIdx.y; i < 32; i += 8)
        tile[i][threadIdx.x] = src[(size_t)(by + i) * C + bx + threadIdx.x];
    __syncthreads();
    for (int i = threadIdx.y; i < 32; i += 8) {
        float v = tile[threadIdx.x][i];
        u16 hi = f2bf(v);
        size_t o = (size_t)(bx + i) * R + by + threadIdx.x;
        dhi[o] = hi;
        dlo[o] = f2bf(v - bf2f(hi));
    }
}

__global__ __launch_bounds__(256) void zero_state(unsigned* __restrict__ h0p,
        unsigned* __restrict__ ctr)
{
    const int i = blockIdx.x * 256 + threadIdx.x;   // grid 1024*256 = 262144
    h0p[i] = 0;
    if (i < 8) ctr[i * 32] = 0;
}

// ---- persistent LSTM: all 128 steps, both encoders (512 batch rows) ----
// 256 blocks x 512 threads (8 waves). rowTile = bid&7 (64 rows, XCD-local group),
// hidTile = bid>>3 (16 hid cols). Quad0: x-part + h ks0..3 + reduce + gates + publish.
// Quad1: h ks4..15 -> LDS partials.
__global__ __launch_bounds__(512, 2) void lstm_persist(
        const float* __restrict__ emb, const int* __restrict__ qtok, const int* __restrict__ rtok,
        const int* __restrict__ qlen, const int* __restrict__ rlen,
        const u16* __restrict__ Wt_hi, const u16* __restrict__ Wt_lo,   // [2048][768]
        const float* __restrict__ bias, const float* __restrict__ wi,
        const float* __restrict__ wf, const float* __restrict__ wo,
        unsigned* __restrict__ h0p, unsigned* __restrict__ h1p,         // packed h planes
        unsigned* __restrict__ ctr)
{
    extern __shared__ char smem[];
    u16* whi_h = (u16*)smem;                                   // 64 KiB W_hi h-part
    f32x4 (*pbuf)[64][5] = (f32x4(*)[64][5])(smem + 65536);    // 20 KiB partials (pad slot 5)

    const int tid = threadIdx.x, lane = tid & 63, wv = tid >> 6;   // wv 0..7
    const int quad = wv >> 2, w = wv & 3;
    const int bid = blockIdx.x;
    const int rowTile = bid & 7, hidTile = bid >> 3;
    const int row0 = rowTile * 64 + w * 16, hid0 = hidTile * 16;
    const int frow = lane & 15, kgrp = lane >> 4;
    const int sw = (frow & 7) << 4;

    // ---- stage h-part W_hi into LDS (once): 64 W-rows x 64 chunks of 16B ----
    for (int i = tid; i < 4096; i += 512) {
        const int gc = i >> 6, c16 = i & 63;
        const int g = gc >> 4, cc = gc & 15;
        const s16x8 v = *(const s16x8*)(Wt_hi + (size_t)(g * 512 + hid0 + cc) * 768 + 256 + c16 * 8);
        *(s16x8*)((char*)whi_h + ((gc * 1024 + c16 * 16) ^ ((gc & 7) << 4))) = v;
    }

    const int   ohid = hid0 + frow;
    const float bi  = bias[ohid];
    const float bj  = bias[512 + ohid];
    const float bff = bias[1024 + ohid];
    const float bo  = bias[1536 + ohid];
    const float wiv = wi[ohid], wfv = wf[ohid], wov = wo[ohid];
    const int   arow = row0 + frow;
    const int*  tokp = (arow < 256) ? (qtok + arow * 128) : (rtok + (arow - 256) * 128);
    const u16*  whi_base[4];
    const u16*  wlo_base[4];
    #pragma unroll
    for (int g = 0; g < 4; ++g) {
        whi_base[g] = Wt_hi + (size_t)(g * 512 + hid0 + frow) * 768;
        wlo_base[g] = Wt_lo + (size_t)(g * 512 + hid0 + frow) * 768;
    }
    int lenv[4];
    #pragma unroll
    for (int r = 0; r < 4; ++r) {
        const int rr = row0 + kgrp * 4 + r;
        lenv[r] = (rr < 256) ? qlen[rr] : rlen[rr - 256];
    }
    float c_reg[4] = {0, 0, 0, 0}, h_reg[4] = {0, 0, 0, 0};

    __syncthreads();   // LDS W staged

    unsigned* myctr = ctr + rowTile * 32;

    for (int t = 0; t < 128; ++t) {
        const unsigned* rd = (t & 1) ? h1p : h0p;
        unsigned*       wr = (t & 1) ? h0p : h1p;

        f32x4 acc[4] = {{0,0,0,0},{0,0,0,0},{0,0,0,0},{0,0,0,0}};

        if (quad == 0) {
            // ---- x-part (token-dependent only; before the poll) ----
            const int    tok  = tokp[t];
            const float* xrow = emb + (size_t)tok * 256 + kgrp * 8;
            f32x4 fv[16];
            #pragma unroll
            for (int i = 0; i < 16; ++i)
                fv[i] = *(const f32x4*)(xrow + (i >> 1) * 32 + (i & 1) * 4);

            #pragma unroll
            for (int ks = 0; ks < 8; ++ks) {
                const f32x4 v0 = fv[2 * ks], v1 = fv[2 * ks + 1];
                const float vv[8] = {v0[0], v0[1], v0[2], v0[3], v1[0], v1[1], v1[2], v1[3]};
                s16x8 xh, xl;
                #pragma unroll
                for (int e = 0; e < 8; ++e) {
                    const u16 hb = f2bf(vv[e]);
                    xh[e] = (short)hb;
                    xl[e] = (short)f2bf(vv[e] - bf2f(hb));
                }
                const int kk = ks * 32 + kgrp * 8;
                #pragma unroll
                for (int g = 0; g < 4; ++g) {
                    const s16x8 bh = *(const s16x8*)(whi_base[g] + kk);
                    const s16x8 bl = *(const s16x8*)(wlo_base[g] + kk);
                    acc[g] = MFMA(xh, bh, acc[g]);
                    acc[g] = MFMA(xl, bh, acc[g]);
                    acc[g] = MFMA(xh, bl, acc[g]);
                }
            }
        }

        // ---- wave-autonomous wait: 128 publishes (32 blocks x 4 quad0-waves)/step ----
        if (lane == 0) {
            const unsigned target = 128u * (unsigned)t;
            while (__hip_atomic_load(myctr, __ATOMIC_RELAXED, __HIP_MEMORY_SCOPE_AGENT) < target)
                __builtin_amdgcn_s_sleep(2);
        }
        asm volatile("" ::: "memory");

        const unsigned* hrd = rd + arow * 512 + kgrp * 8;

        if (quad == 0) {
            // ---- h ks0..3: batch 16 u64 loads, then consume ----
            u64 hv[16];
            #pragma unroll
            for (int i = 0; i < 16; ++i)
                hv[i] = __hip_atomic_load((const u64*)(hrd + (i >> 2) * 32 + (i & 3) * 2),
                                          __ATOMIC_RELAXED, __HIP_MEMORY_SCOPE_AGENT);
            __builtin_amdgcn_sched_barrier(0);
            #pragma unroll
            for (int j = 0; j < 4; ++j) {
                const int kh = j * 32;
                s16x8 ah, al;
                #pragma unroll
                for (int i = 0; i < 4; ++i) unpack_h(hv[j * 4 + i], ah, al, i);
                #pragma unroll
                for (int g = 0; g < 4; ++g) {
                    const int gr = g * 16 + frow;
                    const s16x8 bh = *(const s16x8*)((const char*)whi_h + ((gr * 1024 + (kh + kgrp * 8) * 2) ^ sw));
                    const s16x8 bl = *(const s16x8*)(wlo_base[g] + 256 + kh + kgrp * 8);
                    acc[g] = MFMA(ah, bh, acc[g]);
                    acc[g] = MFMA(al, bh, acc[g]);
                    acc[g] = MFMA(ah, bl, acc[g]);
                    acc[g] = MFMA(al, bl, acc[g]);
                }
            }
        } else {
            // ---- h ks4..15 in two halves of 6 ks (24 u64 batches) ----
            #pragma unroll
            for (int half = 0; half < 2; ++half) {
                const int ks0 = 4 + half * 6;
                u64 hv[24];
                #pragma unroll
                for (int i = 0; i < 24; ++i)
                    hv[i] = __hip_atomic_load((const u64*)(hrd + (ks0 + (i >> 2)) * 32 + (i & 3) * 2),
                                              __ATOMIC_RELAXED, __HIP_MEMORY_SCOPE_AGENT);
                __builtin_amdgcn_sched_barrier(0);
                #pragma unroll
                for (int j = 0; j < 6; ++j) {
                    const int kh = (ks0 + j) * 32;
                    s16x8 ah, al;
                    #pragma unroll
                    for (int i = 0; i < 4; ++i) unpack_h(hv[j * 4 + i], ah, al, i);
                    #pragma unroll
                    for (int g = 0; g < 4; ++g) {
                        const int gr = g * 16 + frow;
                        const s16x8 bh = *(const s16x8*)((const char*)whi_h + ((gr * 1024 + (kh + kgrp * 8) * 2) ^ sw));
                        const s16x8 bl = *(const s16x8*)(wlo_base[g] + 256 + kh + kgrp * 8);
                        acc[g] = MFMA(ah, bh, acc[g]);
                        acc[g] = MFMA(al, bh, acc[g]);
                        acc[g] = MFMA(ah, bl, acc[g]);
                        acc[g] = MFMA(al, bl, acc[g]);
                    }
                }
            }
            // publish partials to LDS
            #pragma unroll
            for (int g = 0; g < 4; ++g)
                pbuf[w][lane][g] = acc[g];
        }

        __syncthreads();   // quad1 partials visible; quad0 h-MFMAs done

        if (quad == 0) {
            // ---- reduce + gates + store + publish ----
            #pragma unroll
            for (int g = 0; g < 4; ++g) {
                const f32x4 pb = pbuf[w][lane][g];
                acc[g][0] += pb[0]; acc[g][1] += pb[1];
                acc[g][2] += pb[2]; acc[g][3] += pb[3];
            }
            #pragma unroll
            for (int r = 0; r < 4; ++r) {
                const float cold = c_reg[r];
                const float ig = sigm(acc[0][r] + bi + wiv * cold);
                const float jg = tanhf(acc[1][r] + bj);
                const float fg = sigm(acc[2][r] + bff + wfv * cold + 2.0f);
                const float cn = fg * cold + ig * jg;
                const float og = sigm(acc[3][r] + bo + wov * cn);
                const float hn = og * tanhf(cn);
                const bool upd = (t < lenv[r]);
                c_reg[r] = upd ? cn : c_reg[r];
                h_reg[r] = upd ? hn : h_reg[r];
                const int off = (row0 + kgrp * 4 + r) * 512 + ohid;
                const u16 hb = f2bf(h_reg[r]);
                const u16 lb = f2bf(h_reg[r] - bf2f(hb));
                __hip_atomic_store(wr + off, ((unsigned)lb << 16) | (unsigned)hb,
                                   __ATOMIC_RELAXED, __HIP_MEMORY_SCOPE_AGENT);
            }
            asm volatile("s_waitcnt vmcnt(0)" ::: "memory");
            if (lane == 0)
                __hip_atomic_fetch_add(myctr, 1u, __ATOMIC_RELAXED, __HIP_MEMORY_SCOPE_AGENT);
        }
        asm volatile("" ::: "memory");
    }
}

// ---- qt[256][512] = q_h @ M (MFMA, h from packed plane, M hi+lo, 4 products) ----
__global__ __launch_bounds__(256) void qt_kernel(
        const unsigned* __restrict__ hpk,
        const u16* __restrict__ Mt_hi, const u16* __restrict__ Mt_lo, float* __restrict__ qt)
{
    const int tid = threadIdx.x, lane = tid & 63, w = tid >> 6;
    const int wr = w >> 1, wc = w & 1;
    const int row0 = blockIdx.x * 32 + wr * 16;
    const int col0 = blockIdx.y * 32 + wc * 16;
    const int frow = lane & 15, kgrp = lane >> 4;
    f32x4 acc = {0, 0, 0, 0};
    const unsigned* ap = hpk + (row0 + frow) * 512 + kgrp * 8;
    const u16* bph = Mt_hi + (col0 + frow) * 512 + kgrp * 8;
    const u16* bpl = Mt_lo + (col0 + frow) * 512 + kgrp * 8;
    #pragma unroll 4
    for (int ks = 0; ks < 16; ++ks) {
        const u32x4 a0 = *(const u32x4*)(ap + ks * 32);
        const u32x4 a1 = *(const u32x4*)(ap + ks * 32 + 4);
        s16x8 ah, al;
        #pragma unroll
        for (int i = 0; i < 4; ++i) {
            ah[i]     = (short)(u16)a0[i];
            al[i]     = (short)(u16)(a0[i] >> 16);
            ah[4 + i] = (short)(u16)a1[i];
            al[4 + i] = (short)(u16)(a1[i] >> 16);
        }
        const s16x8 bh = *(const s16x8*)(bph + ks * 32);
        const s16x8 bl = *(const s16x8*)(bpl + ks * 32);
        acc = MFMA(ah, bh, acc);
        acc = MFMA(al, bh, acc);
        acc = MFMA(ah, bl, acc);
        acc = MFMA(al, bl, acc);
    }
    #pragma unroll
    for (int r = 0; r < 4; ++r)
        qt[(row0 + kgrp * 4 + r) * 512 + col0 + frow] = acc[r];
}

// ---- final MLP: 1280 rows, one wave per row ----
__global__ __launch_bounds__(256) void dense_out(const float* __restrict__ qt,
        const unsigned* __restrict__ hpk,
        const float* __restrict__ W1, const float* __restrict__ b1,
        const float* __restrict__ W2, const float* __restrict__ b2, float* __restrict__ out)
{
    const int r    = blockIdx.x * 4 + (threadIdx.x >> 6);
    const int lane = threadIdx.x & 63;
    int qi, ri;
    if (r < 256) { qi = r; ri = r; }
    else { const int g = (r - 256) >> 8; const int b = (r - 256) & 255; qi = b; ri = (b + g + 1) & 255; }

    float p[10];
    #pragma unroll
    for (int u = 0; u < 10; ++u) p[u] = 0.0f;
    for (int k = lane; k < 512; k += 64) {
        const float xq = qt[qi * 512 + k];
        #pragma unroll
        for (int u = 0; u < 10; ++u) p[u] += xq * W1[k * 10 + u];
    }
    for (int k = lane; k < 512; k += 64) {
        const unsigned v = hpk[(256 + ri) * 512 + k];
        const float xr = bf2f((u16)v) + bf2f((u16)(v >> 16));
        #pragma unroll
        for (int u = 0; u < 10; ++u) p[u] += xr * W1[(512 + k) * 10 + u];
    }
    #pragma unroll
    for (int off = 32; off; off >>= 1) {
        #pragma unroll
        for (int u = 0; u < 10; ++u) p[u] += __shfl_xor(p[u], off);
    }
    float s = b2[0];
    #pragma unroll
    for (int u = 0; u < 10; ++u) {
        const float h1 = fmaxf(p[u] + b1[u], 0.0f);
        s += h1 * W2[u];
    }
    if (lane == 0) out[r] = fmaxf(s, 0.0f);
}

extern "C" void kernel_launch(void* const* d_in, const int* in_sizes, int n_in,
                              void* d_out, int out_size, void* d_ws, size_t ws_size,
                              hipStream_t stream)
{
    const float* emb  = (const float*)d_in[0];
    const float* Wk   = (const float*)d_in[1];
    const float* bias = (const float*)d_in[2];
    const float* wi   = (const float*)d_in[3];
    const float* wf   = (const float*)d_in[4];
    const float* wo   = (const float*)d_in[5];
    const float* M    = (const float*)d_in[6];
    const float* W1   = (const float*)d_in[7];
    const float* b1   = (const float*)d_in[8];
    const float* W2   = (const float*)d_in[9];
    const float* b2   = (const float*)d_in[10];
    const int*   qtok = (const int*)d_in[11];
    const int*   rtok = (const int*)d_in[12];
    const int*   qlen = (const int*)d_in[13];
    const int*   rlen = (const int*)d_in[14];
    float* out = (float*)d_out;

    // workspace layout (16B-aligned); total ~10.5 MB
    char* ws = (char*)d_ws;
    u16*      Wt_hi = (u16*)(ws + 0);            // 3,145,728
    u16*      Wt_lo = (u16*)(ws + 3145728);      // 3,145,728
    u16*      Mt_hi = (u16*)(ws + 6291456);      //   524,288
    u16*      Mt_lo = (u16*)(ws + 6815744);      //   524,288
    unsigned* h0p   = (unsigned*)(ws + 7340032); // 1,048,576 (packed lo|hi)
    unsigned* h1p   = (unsigned*)(ws + 8388608); // 1,048,576
    float*    qt    = (float*)(ws + 9437184);    //   524,288
    unsigned* ctr   = (unsigned*)(ws + 9961472); // 8 counters @ 128B stride

    transpose_split<<<dim3(64, 24), dim3(32, 8), 0, stream>>>(Wk, Wt_hi, Wt_lo, 768, 2048);
    transpose_split<<<dim3(16, 16), dim3(32, 8), 0, stream>>>(M, Mt_hi, Mt_lo, 512, 512);
    zero_state<<<1024, 256, 0, stream>>>(h0p, ctr);

    // 84 KiB dynamic LDS (mechanism proven rounds 11/12)
    hipFuncSetAttribute((const void*)lstm_persist,
                        hipFuncAttributeMaxDynamicSharedMemorySize, 86016);
    lstm_persist<<<256, 512, 86016, stream>>>(emb, qtok, rtok, qlen, rlen,
                                              Wt_hi, Wt_lo, bias, wi, wf, wo,
                                              h0p, h1p, ctr);

    // 128 steps (even) => final h lives in h0p
    qt_kernel<<<dim3(8, 16), 256, 0, stream>>>(h0p, Mt_hi, Mt_lo, qt);
    dense_out<<<320, 256, 0, stream>>>(qt, h0p, W1, b1, W2, b2, out);
}

// Round 20
// 1890.988 us; speedup vs baseline: 2.4931x; 2.4931x over previous
//
#include <hip/hip_runtime.h>

// DualEncoderLSTMDense: dual peephole-LSTM encoders (shared weights) + M-projection + tiny MLP.
// B=256, L=128, E=256, H=512, VOCAB=90000, NUM_NEG=4, forget_bias=2.0.
//
// Round 20: R16 (best: 2990us kernel, proven geometry 256x256, rowTile=bid&7) + h-part
// W_lo moved from L2-stream into dynamic LDS (128KB total; mechanism proven R11/R12 —
// R15's failure was its inline-asm loads, not the LDS). Pure subtraction: streamed W
// per block per step 128KB -> 64KB (per-XCD union 4MB -> 2MB), h-part bl becomes a
// conflict-free swizzled ds_read_b128. Values and MFMA order bit-identical to R16
// (absmax 1.953125e-3). Everything else untouched.

typedef unsigned short u16;
typedef unsigned long long u64;
typedef __attribute__((ext_vector_type(8))) short    s16x8;
typedef __attribute__((ext_vector_type(4))) float    f32x4;
typedef __attribute__((ext_vector_type(4))) unsigned u32x4;

#define MFMA(a, b, c) __builtin_amdgcn_mfma_f32_16x16x32_bf16((a), (b), (c), 0, 0, 0)

__device__ __forceinline__ u16 f2bf(float f) {
    union { float f; unsigned u; } v; v.f = f;
    unsigned r = v.u + 0x7FFFu + ((v.u >> 16) & 1u);
    return (u16)(r >> 16);
}
__device__ __forceinline__ float bf2f(u16 h) {
    union { unsigned u; float f; } v; v.u = ((unsigned)h) << 16;
    return v.f;
}
__device__ __forceinline__ float sigm(float x) { return 1.0f / (1.0f + expf(-x)); }

// ---- transpose fp32 [R][C] -> bf16 hi/lo planes [C][R] ----
__global__ __launch_bounds__(256) void transpose_split(const float* __restrict__ src,
        u16* __restrict__ dhi, u16* __restrict__ dlo, int R, int C)
{
    __shared__ float tile[32][33];
    const int bx = blockIdx.x * 32;
    const int by = blockIdx.y * 32;
    for (int i = threadIdx.y; i < 32; i += 8)
        tile[i][threadIdx.x] = src[(size_t)(by + i) * C + bx + threadIdx.x];
    __syncthreads();
    for (int i = threadIdx.y; i < 32; i += 8) {
        float v = tile[threadIdx.x][i];
        u16 hi = f2bf(v);
        size_t o = (size_t)(bx + i) * R + by + threadIdx.x;
        dhi[o] = hi;
        dlo[o] = f2bf(v - bf2f(hi));
    }
}

__global__ __launch_bounds__(256) void zero_state(unsigned* __restrict__ h0p,
        unsigned* __restrict__ ctr)
{
    const int i = blockIdx.x * 256 + threadIdx.x;   // grid 1024*256 = 262144
    h0p[i] = 0;
    if (i < 8) ctr[i * 32] = 0;
}

// ---- persistent LSTM: all 128 steps, both encoders (512 batch rows) ----
// 256 blocks (1/CU): rowTile = bid&7 (64 batch rows), hidTile = bid>>3 (16 hid cols).
// Dynamic LDS 128 KiB: [0,64K) W_hi h-part, [64K,128K) W_lo h-part (both XOR-swizzled).
__global__ __launch_bounds__(256, 1) void lstm_persist(
        const float* __restrict__ emb, const int* __restrict__ qtok, const int* __restrict__ rtok,
        const int* __restrict__ qlen, const int* __restrict__ rlen,
        const u16* __restrict__ Wt_hi, const u16* __restrict__ Wt_lo,   // [2048][768]
        const float* __restrict__ bias, const float* __restrict__ wi,
        const float* __restrict__ wf, const float* __restrict__ wo,
        unsigned* __restrict__ h0p, unsigned* __restrict__ h1p,         // packed h planes
        unsigned* __restrict__ ctr)
{
    extern __shared__ char smem[];
    u16* whi_h = (u16*)smem;             // 64 KiB
    u16* wlo_h = (u16*)(smem + 65536);   // 64 KiB

    const int tid = threadIdx.x, lane = tid & 63, w = tid >> 6;
    const int bid = blockIdx.x;
    const int rowTile = bid & 7, hidTile = bid >> 3;
    const int row0 = rowTile * 64 + w * 16, hid0 = hidTile * 16;
    const int frow = lane & 15, kgrp = lane >> 4;
    const int sw = (frow & 7) << 4;

    // ---- stage h-part W_hi AND W_lo into LDS (once): 64 W-rows x 64 chunks of 16B ----
    for (int i = tid; i < 4096; i += 256) {
        const int gc = i >> 6, c16 = i & 63;
        const int g = gc >> 4, cc = gc & 15;
        const size_t srcoff = (size_t)(g * 512 + hid0 + cc) * 768 + 256 + c16 * 8;
        const int dst = (gc * 1024 + c16 * 16) ^ ((gc & 7) << 4);
        *(s16x8*)((char*)whi_h + dst) = *(const s16x8*)(Wt_hi + srcoff);
        *(s16x8*)((char*)wlo_h + dst) = *(const s16x8*)(Wt_lo + srcoff);
    }

    const int   ohid = hid0 + frow;
    const float bi  = bias[ohid];
    const float bj  = bias[512 + ohid];
    const float bff = bias[1024 + ohid];
    const float bo  = bias[1536 + ohid];
    const float wiv = wi[ohid], wfv = wf[ohid], wov = wo[ohid];
    const int   arow = row0 + frow;
    const int*  tokp = (arow < 256) ? (qtok + arow * 128) : (rtok + (arow - 256) * 128);
    const u16*  whi_base[4];
    const u16*  wlo_base[4];
    #pragma unroll
    for (int g = 0; g < 4; ++g) {
        whi_base[g] = Wt_hi + (size_t)(g * 512 + hid0 + frow) * 768;
        wlo_base[g] = Wt_lo + (size_t)(g * 512 + hid0 + frow) * 768;
    }
    int lenv[4];
    #pragma unroll
    for (int r = 0; r < 4; ++r) {
        const int rr = row0 + kgrp * 4 + r;
        lenv[r] = (rr < 256) ? qlen[rr] : rlen[rr - 256];
    }
    float c_reg[4] = {0, 0, 0, 0}, h_reg[4] = {0, 0, 0, 0};

    __syncthreads();   // LDS W staged

    unsigned* myctr = ctr + rowTile * 32;

    for (int t = 0; t < 128; ++t) {
        const unsigned* rd = (t & 1) ? h1p : h0p;
        unsigned*       wr = (t & 1) ? h0p : h1p;

        // ---- x-part (token-dependent only; overlaps barrier stragglers) ----
        const int    tok  = tokp[t];
        const float* xrow = emb + (size_t)tok * 256 + kgrp * 8;
        f32x4 fv[16];
        #pragma unroll
        for (int i = 0; i < 16; ++i)
            fv[i] = *(const f32x4*)(xrow + (i >> 1) * 32 + (i & 1) * 4);

        f32x4 acc[4] = {{0,0,0,0},{0,0,0,0},{0,0,0,0},{0,0,0,0}};

        // x-part, K 0..255: split fp32 gather into 2 planes; bh/bl streamed (L2); 3 products
        #pragma unroll
        for (int ks = 0; ks < 8; ++ks) {
            const f32x4 v0 = fv[2 * ks], v1 = fv[2 * ks + 1];
            const float vv[8] = {v0[0], v0[1], v0[2], v0[3], v1[0], v1[1], v1[2], v1[3]};
            s16x8 xh, xl;
            #pragma unroll
            for (int e = 0; e < 8; ++e) {
                const u16 hb = f2bf(vv[e]);
                xh[e] = (short)hb;
                xl[e] = (short)f2bf(vv[e] - bf2f(hb));
            }
            const int kk = ks * 32 + kgrp * 8;
            #pragma unroll
            for (int g = 0; g < 4; ++g) {
                const s16x8 bh = *(const s16x8*)(whi_base[g] + kk);
                const s16x8 bl = *(const s16x8*)(wlo_base[g] + kk);
                acc[g] = MFMA(xh, bh, acc[g]);
                acc[g] = MFMA(xl, bh, acc[g]);
                acc[g] = MFMA(xh, bl, acc[g]);
            }
        }

        // ---- wave-autonomous wait: 128 publishes (32 blocks x 4 waves) per step ----
        if (lane == 0) {
            const unsigned target = 128u * (unsigned)t;
            while (__hip_atomic_load(myctr, __ATOMIC_RELAXED, __HIP_MEMORY_SCOPE_AGENT) < target)
                __builtin_amdgcn_s_sleep(2);
        }
        asm volatile("" ::: "memory");

        const unsigned* hrd = rd + arow * 512 + kgrp * 8;

        // ---- h-part, K 256..767, in 2 halves of 8 ks: batched relaxed atomic loads;
        //      bh AND bl from LDS (swizzled ds_read_b128). Same values/order as R16. ----
        #pragma unroll
        for (int half = 0; half < 2; ++half) {
            u64 hv[32];
            #pragma unroll
            for (int i = 0; i < 32; ++i) {
                const int ks = half * 8 + (i >> 2);
                hv[i] = __hip_atomic_load((const u64*)(hrd + ks * 32 + (i & 3) * 2),
                                          __ATOMIC_RELAXED, __HIP_MEMORY_SCOPE_AGENT);
            }
            __builtin_amdgcn_sched_barrier(0);   // keep loads batched ahead of consumption
            #pragma unroll
            for (int j = 0; j < 8; ++j) {
                const int ks = half * 8 + j;
                const int kh = ks * 32;
                s16x8 ah, al;
                #pragma unroll
                for (int i = 0; i < 4; ++i) {
                    const u64 v = hv[j * 4 + i];
                    const unsigned w0 = (unsigned)v, w1 = (unsigned)(v >> 32);
                    ah[2 * i]     = (short)(u16)w0;
                    al[2 * i]     = (short)(u16)(w0 >> 16);
                    ah[2 * i + 1] = (short)(u16)w1;
                    al[2 * i + 1] = (short)(u16)(w1 >> 16);
                }
                #pragma unroll
                for (int g = 0; g < 4; ++g) {
                    const int gr = g * 16 + frow;
                    const int wo_ = (gr * 1024 + (kh + kgrp * 8) * 2) ^ sw;
                    const s16x8 bh = *(const s16x8*)((const char*)whi_h + wo_);
                    const s16x8 bl = *(const s16x8*)((const char*)wlo_h + wo_);
                    acc[g] = MFMA(ah, bh, acc[g]);
                    acc[g] = MFMA(al, bh, acc[g]);
                    acc[g] = MFMA(ah, bl, acc[g]);
                    acc[g] = MFMA(al, bl, acc[g]);
                }
            }
        }

        // ---- gates + peepholes + masking; publish h packed via sc1 atomic store ----
        #pragma unroll
        for (int r = 0; r < 4; ++r) {
            const float cold = c_reg[r];
            const float ig = sigm(acc[0][r] + bi + wiv * cold);
            const float jg = tanhf(acc[1][r] + bj);
            const float fg = sigm(acc[2][r] + bff + wfv * cold + 2.0f);
            const float cn = fg * cold + ig * jg;
            const float og = sigm(acc[3][r] + bo + wov * cn);
            const float hn = og * tanhf(cn);
            const bool upd = (t < lenv[r]);
            c_reg[r] = upd ? cn : c_reg[r];
            h_reg[r] = upd ? hn : h_reg[r];
            const int off = (row0 + kgrp * 4 + r) * 512 + ohid;
            const u16 hb = f2bf(h_reg[r]);
            const u16 lb = f2bf(h_reg[r] - bf2f(hb));
            __hip_atomic_store(wr + off, ((unsigned)lb << 16) | (unsigned)hb,
                               __ATOMIC_RELAXED, __HIP_MEMORY_SCOPE_AGENT);
        }

        // ---- per-wave publish: drain this wave's stores, one relaxed add ----
        asm volatile("s_waitcnt vmcnt(0)" ::: "memory");
        if (lane == 0)
            __hip_atomic_fetch_add(myctr, 1u, __ATOMIC_RELAXED, __HIP_MEMORY_SCOPE_AGENT);
        asm volatile("" ::: "memory");
    }
}

// ---- qt[256][512] = q_h @ M (MFMA, h from packed plane, M hi+lo, 4 products) ----
__global__ __launch_bounds__(256) void qt_kernel(
        const unsigned* __restrict__ hpk,
        const u16* __restrict__ Mt_hi, const u16* __restrict__ Mt_lo, float* __restrict__ qt)
{
    const int tid = threadIdx.x, lane = tid & 63, w = tid >> 6;
    const int wr = w >> 1, wc = w & 1;
    const int row0 = blockIdx.x * 32 + wr * 16;
    const int col0 = blockIdx.y * 32 + wc * 16;
    const int frow = lane & 15, kgrp = lane >> 4;
    f32x4 acc = {0, 0, 0, 0};
    const unsigned* ap = hpk + (row0 + frow) * 512 + kgrp * 8;
    const u16* bph = Mt_hi + (col0 + frow) * 512 + kgrp * 8;
    const u16* bpl = Mt_lo + (col0 + frow) * 512 + kgrp * 8;
    #pragma unroll 4
    for (int ks = 0; ks < 16; ++ks) {
        const u32x4 a0 = *(const u32x4*)(ap + ks * 32);
        const u32x4 a1 = *(const u32x4*)(ap + ks * 32 + 4);
        s16x8 ah, al;
        #pragma unroll
        for (int i = 0; i < 4; ++i) {
            ah[i]     = (short)(u16)a0[i];
            al[i]     = (short)(u16)(a0[i] >> 16);
            ah[4 + i] = (short)(u16)a1[i];
            al[4 + i] = (short)(u16)(a1[i] >> 16);
        }
        const s16x8 bh = *(const s16x8*)(bph + ks * 32);
        const s16x8 bl = *(const s16x8*)(bpl + ks * 32);
        acc = MFMA(ah, bh, acc);
        acc = MFMA(al, bh, acc);
        acc = MFMA(ah, bl, acc);
        acc = MFMA(al, bl, acc);
    }
    #pragma unroll
    for (int r = 0; r < 4; ++r)
        qt[(row0 + kgrp * 4 + r) * 512 + col0 + frow] = acc[r];
}

// ---- final MLP: 1280 rows, one wave per row ----
__global__ __launch_bounds__(256) void dense_out(const float* __restrict__ qt,
        const unsigned* __restrict__ hpk,
        const float* __restrict__ W1, const float* __restrict__ b1,
        const float* __restrict__ W2, const float* __restrict__ b2, float* __restrict__ out)
{
    const int r    = blockIdx.x * 4 + (threadIdx.x >> 6);
    const int lane = threadIdx.x & 63;
    int qi, ri;
    if (r < 256) { qi = r; ri = r; }
    else { const int g = (r - 256) >> 8; const int b = (r - 256) & 255; qi = b; ri = (b + g + 1) & 255; }

    float p[10];
    #pragma unroll
    for (int u = 0; u < 10; ++u) p[u] = 0.0f;
    for (int k = lane; k < 512; k += 64) {
        const float xq = qt[qi * 512 + k];
        #pragma unroll
        for (int u = 0; u < 10; ++u) p[u] += xq * W1[k * 10 + u];
    }
    for (int k = lane; k < 512; k += 64) {
        const unsigned v = hpk[(256 + ri) * 512 + k];
        const float xr = bf2f((u16)v) + bf2f((u16)(v >> 16));
        #pragma unroll
        for (int u = 0; u < 10; ++u) p[u] += xr * W1[(512 + k) * 10 + u];
    }
    #pragma unroll
    for (int off = 32; off; off >>= 1) {
        #pragma unroll
        for (int u = 0; u < 10; ++u) p[u] += __shfl_xor(p[u], off);
    }
    float s = b2[0];
    #pragma unroll
    for (int u = 0; u < 10; ++u) {
        const float h1 = fmaxf(p[u] + b1[u], 0.0f);
        s += h1 * W2[u];
    }
    if (lane == 0) out[r] = fmaxf(s, 0.0f);
}

extern "C" void kernel_launch(void* const* d_in, const int* in_sizes, int n_in,
                              void* d_out, int out_size, void* d_ws, size_t ws_size,
                              hipStream_t stream)
{
    const float* emb  = (const float*)d_in[0];
    const float* Wk   = (const float*)d_in[1];
    const float* bias = (const float*)d_in[2];
    const float* wi   = (const float*)d_in[3];
    const float* wf   = (const float*)d_in[4];
    const float* wo   = (const float*)d_in[5];
    const float* M    = (const float*)d_in[6];
    const float* W1   = (const float*)d_in[7];
    const float* b1   = (const float*)d_in[8];
    const float* W2   = (const float*)d_in[9];
    const float* b2   = (const float*)d_in[10];
    const int*   qtok = (const int*)d_in[11];
    const int*   rtok = (const int*)d_in[12];
    const int*   qlen = (const int*)d_in[13];
    const int*   rlen = (const int*)d_in[14];
    float* out = (float*)d_out;

    // workspace layout (16B-aligned); total ~10.5 MB
    char* ws = (char*)d_ws;
    u16*      Wt_hi = (u16*)(ws + 0);            // 3,145,728
    u16*      Wt_lo = (u16*)(ws + 3145728);      // 3,145,728
    u16*      Mt_hi = (u16*)(ws + 6291456);      //   524,288
    u16*      Mt_lo = (u16*)(ws + 6815744);      //   524,288
    unsigned* h0p   = (unsigned*)(ws + 7340032); // 1,048,576 (packed lo|hi)
    unsigned* h1p   = (unsigned*)(ws + 8388608); // 1,048,576
    float*    qt    = (float*)(ws + 9437184);    //   524,288
    unsigned* ctr   = (unsigned*)(ws + 9961472); // 8 counters @ 128B stride

    transpose_split<<<dim3(64, 24), dim3(32, 8), 0, stream>>>(Wk, Wt_hi, Wt_lo, 768, 2048);
    transpose_split<<<dim3(16, 16), dim3(32, 8), 0, stream>>>(M, Mt_hi, Mt_lo, 512, 512);
    zero_state<<<1024, 256, 0, stream>>>(h0p, ctr);

    // 128 KiB dynamic LDS (mechanism proven rounds 11/12)
    hipFuncSetAttribute((const void*)lstm_persist,
                        hipFuncAttributeMaxDynamicSharedMemorySize, 131072);
    lstm_persist<<<256, 256, 131072, stream>>>(emb, qtok, rtok, qlen, rlen,
                                               Wt_hi, Wt_lo, bias, wi, wf, wo,
                                               h0p, h1p, ctr);

    // 128 steps (even) => final h lives in h0p
    qt_kernel<<<dim3(8, 16), 256, 0, stream>>>(h0p, Mt_hi, Mt_lo, qt);
    dense_out<<<320, 256, 0, stream>>>(qt, h0p, W1, b1, W2, b2, out);
}

// Round 21
// 1850.009 us; speedup vs baseline: 2.5484x; 1.0222x over previous
//
#include <hip/hip_runtime.h>

// DualEncoderLSTMDense: dual peephole-LSTM encoders (shared weights) + M-projection + tiny MLP.
// B=256, L=128, E=256, H=512, VOCAB=90000, NUM_NEG=4, forget_bias=2.0.
//
// Round 21: R20 (best: 2000us kernel — h-part W_hi+W_lo both in 128KB dynamic LDS,
// geometry 256x256, rowTile=bid&7) + PER-BLOCK publish: vmcnt(0)/wave -> __syncthreads
// -> ONE atomicAdd by tid0 (32 RMWs/step instead of 128; RMWs on one line serialize at
// the coherence point, ~50-100cy each -> up to ~3-5us/step barrier tail). Poll stays
// per-wave relaxed loads (target 32*t; reads don't serialize). Everything else identical
// to R20 -> bit-identical output (absmax 1.953125e-3).

typedef unsigned short u16;
typedef unsigned long long u64;
typedef __attribute__((ext_vector_type(8))) short    s16x8;
typedef __attribute__((ext_vector_type(4))) float    f32x4;
typedef __attribute__((ext_vector_type(4))) unsigned u32x4;

#define MFMA(a, b, c) __builtin_amdgcn_mfma_f32_16x16x32_bf16((a), (b), (c), 0, 0, 0)

__device__ __forceinline__ u16 f2bf(float f) {
    union { float f; unsigned u; } v; v.f = f;
    unsigned r = v.u + 0x7FFFu + ((v.u >> 16) & 1u);
    return (u16)(r >> 16);
}
__device__ __forceinline__ float bf2f(u16 h) {
    union { unsigned u; float f; } v; v.u = ((unsigned)h) << 16;
    return v.f;
}
__device__ __forceinline__ float sigm(float x) { return 1.0f / (1.0f + expf(-x)); }

// ---- transpose fp32 [R][C] -> bf16 hi/lo planes [C][R] ----
__global__ __launch_bounds__(256) void transpose_split(const float* __restrict__ src,
        u16* __restrict__ dhi, u16* __restrict__ dlo, int R, int C)
{
    __shared__ float tile[32][33];
    const int bx = blockIdx.x * 32;
    const int by = blockIdx.y * 32;
    for (int i = threadIdx.y; i < 32; i += 8)
        tile[i][threadIdx.x] = src[(size_t)(by + i) * C + bx + threadIdx.x];
    __syncthreads();
    for (int i = threadIdx.y; i < 32; i += 8) {
        float v = tile[threadIdx.x][i];
        u16 hi = f2bf(v);
        size_t o = (size_t)(bx + i) * R + by + threadIdx.x;
        dhi[o] = hi;
        dlo[o] = f2bf(v - bf2f(hi));
    }
}

__global__ __launch_bounds__(256) void zero_state(unsigned* __restrict__ h0p,
        unsigned* __restrict__ ctr)
{
    const int i = blockIdx.x * 256 + threadIdx.x;   // grid 1024*256 = 262144
    h0p[i] = 0;
    if (i < 8) ctr[i * 32] = 0;
}

// ---- persistent LSTM: all 128 steps, both encoders (512 batch rows) ----
// 256 blocks (1/CU): rowTile = bid&7 (64 batch rows), hidTile = bid>>3 (16 hid cols).
// Dynamic LDS 128 KiB: [0,64K) W_hi h-part, [64K,128K) W_lo h-part (both XOR-swizzled).
__global__ __launch_bounds__(256, 1) void lstm_persist(
        const float* __restrict__ emb, const int* __restrict__ qtok, const int* __restrict__ rtok,
        const int* __restrict__ qlen, const int* __restrict__ rlen,
        const u16* __restrict__ Wt_hi, const u16* __restrict__ Wt_lo,   // [2048][768]
        const float* __restrict__ bias, const float* __restrict__ wi,
        const float* __restrict__ wf, const float* __restrict__ wo,
        unsigned* __restrict__ h0p, unsigned* __restrict__ h1p,         // packed h planes
        unsigned* __restrict__ ctr)
{
    extern __shared__ char smem[];
    u16* whi_h = (u16*)smem;             // 64 KiB
    u16* wlo_h = (u16*)(smem + 65536);   // 64 KiB

    const int tid = threadIdx.x, lane = tid & 63, w = tid >> 6;
    const int bid = blockIdx.x;
    const int rowTile = bid & 7, hidTile = bid >> 3;
    const int row0 = rowTile * 64 + w * 16, hid0 = hidTile * 16;
    const int frow = lane & 15, kgrp = lane >> 4;
    const int sw = (frow & 7) << 4;

    // ---- stage h-part W_hi AND W_lo into LDS (once): 64 W-rows x 64 chunks of 16B ----
    for (int i = tid; i < 4096; i += 256) {
        const int gc = i >> 6, c16 = i & 63;
        const int g = gc >> 4, cc = gc & 15;
        const size_t srcoff = (size_t)(g * 512 + hid0 + cc) * 768 + 256 + c16 * 8;
        const int dst = (gc * 1024 + c16 * 16) ^ ((gc & 7) << 4);
        *(s16x8*)((char*)whi_h + dst) = *(const s16x8*)(Wt_hi + srcoff);
        *(s16x8*)((char*)wlo_h + dst) = *(const s16x8*)(Wt_lo + srcoff);
    }

    const int   ohid = hid0 + frow;
    const float bi  = bias[ohid];
    const float bj  = bias[512 + ohid];
    const float bff = bias[1024 + ohid];
    const float bo  = bias[1536 + ohid];
    const float wiv = wi[ohid], wfv = wf[ohid], wov = wo[ohid];
    const int   arow = row0 + frow;
    const int*  tokp = (arow < 256) ? (qtok + arow * 128) : (rtok + (arow - 256) * 128);
    const u16*  whi_base[4];
    const u16*  wlo_base[4];
    #pragma unroll
    for (int g = 0; g < 4; ++g) {
        whi_base[g] = Wt_hi + (size_t)(g * 512 + hid0 + frow) * 768;
        wlo_base[g] = Wt_lo + (size_t)(g * 512 + hid0 + frow) * 768;
    }
    int lenv[4];
    #pragma unroll
    for (int r = 0; r < 4; ++r) {
        const int rr = row0 + kgrp * 4 + r;
        lenv[r] = (rr < 256) ? qlen[rr] : rlen[rr - 256];
    }
    float c_reg[4] = {0, 0, 0, 0}, h_reg[4] = {0, 0, 0, 0};

    __syncthreads();   // LDS W staged

    unsigned* myctr = ctr + rowTile * 32;

    for (int t = 0; t < 128; ++t) {
        const unsigned* rd = (t & 1) ? h1p : h0p;
        unsigned*       wr = (t & 1) ? h0p : h1p;

        // ---- x-part (token-dependent only; overlaps barrier stragglers) ----
        const int    tok  = tokp[t];
        const float* xrow = emb + (size_t)tok * 256 + kgrp * 8;
        f32x4 fv[16];
        #pragma unroll
        for (int i = 0; i < 16; ++i)
            fv[i] = *(const f32x4*)(xrow + (i >> 1) * 32 + (i & 1) * 4);

        f32x4 acc[4] = {{0,0,0,0},{0,0,0,0},{0,0,0,0},{0,0,0,0}};

        // x-part, K 0..255: split fp32 gather into 2 planes; bh/bl streamed (L2); 3 products
        #pragma unroll
        for (int ks = 0; ks < 8; ++ks) {
            const f32x4 v0 = fv[2 * ks], v1 = fv[2 * ks + 1];
            const float vv[8] = {v0[0], v0[1], v0[2], v0[3], v1[0], v1[1], v1[2], v1[3]};
            s16x8 xh, xl;
            #pragma unroll
            for (int e = 0; e < 8; ++e) {
                const u16 hb = f2bf(vv[e]);
                xh[e] = (short)hb;
                xl[e] = (short)f2bf(vv[e] - bf2f(hb));
            }
            const int kk = ks * 32 + kgrp * 8;
            #pragma unroll
            for (int g = 0; g < 4; ++g) {
                const s16x8 bh = *(const s16x8*)(whi_base[g] + kk);
                const s16x8 bl = *(const s16x8*)(wlo_base[g] + kk);
                acc[g] = MFMA(xh, bh, acc[g]);
                acc[g] = MFMA(xl, bh, acc[g]);
                acc[g] = MFMA(xh, bl, acc[g]);
            }
        }

        // ---- per-wave wait: 32 block-publishes per step ----
        if (lane == 0) {
            const unsigned target = 32u * (unsigned)t;
            while (__hip_atomic_load(myctr, __ATOMIC_RELAXED, __HIP_MEMORY_SCOPE_AGENT) < target)
                __builtin_amdgcn_s_sleep(2);
        }
        asm volatile("" ::: "memory");

        const unsigned* hrd = rd + arow * 512 + kgrp * 8;

        // ---- h-part, K 256..767, in 2 halves of 8 ks: batched relaxed atomic loads;
        //      bh AND bl from LDS (swizzled ds_read_b128). ----
        #pragma unroll
        for (int half = 0; half < 2; ++half) {
            u64 hv[32];
            #pragma unroll
            for (int i = 0; i < 32; ++i) {
                const int ks = half * 8 + (i >> 2);
                hv[i] = __hip_atomic_load((const u64*)(hrd + ks * 32 + (i & 3) * 2),
                                          __ATOMIC_RELAXED, __HIP_MEMORY_SCOPE_AGENT);
            }
            __builtin_amdgcn_sched_barrier(0);   // keep loads batched ahead of consumption
            #pragma unroll
            for (int j = 0; j < 8; ++j) {
                const int ks = half * 8 + j;
                const int kh = ks * 32;
                s16x8 ah, al;
                #pragma unroll
                for (int i = 0; i < 4; ++i) {
                    const u64 v = hv[j * 4 + i];
                    const unsigned w0 = (unsigned)v, w1 = (unsigned)(v >> 32);
                    ah[2 * i]     = (short)(u16)w0;
                    al[2 * i]     = (short)(u16)(w0 >> 16);
                    ah[2 * i + 1] = (short)(u16)w1;
                    al[2 * i + 1] = (short)(u16)(w1 >> 16);
                }
                #pragma unroll
                for (int g = 0; g < 4; ++g) {
                    const int gr = g * 16 + frow;
                    const int wo_ = (gr * 1024 + (kh + kgrp * 8) * 2) ^ sw;
                    const s16x8 bh = *(const s16x8*)((const char*)whi_h + wo_);
                    const s16x8 bl = *(const s16x8*)((const char*)wlo_h + wo_);
                    acc[g] = MFMA(ah, bh, acc[g]);
                    acc[g] = MFMA(al, bh, acc[g]);
                    acc[g] = MFMA(ah, bl, acc[g]);
                    acc[g] = MFMA(al, bl, acc[g]);
                }
            }
        }

        // ---- gates + peepholes + masking; publish h packed via sc1 atomic store ----
        #pragma unroll
        for (int r = 0; r < 4; ++r) {
            const float cold = c_reg[r];
            const float ig = sigm(acc[0][r] + bi + wiv * cold);
            const float jg = tanhf(acc[1][r] + bj);
            const float fg = sigm(acc[2][r] + bff + wfv * cold + 2.0f);
            const float cn = fg * cold + ig * jg;
            const float og = sigm(acc[3][r] + bo + wov * cn);
            const float hn = og * tanhf(cn);
            const bool upd = (t < lenv[r]);
            c_reg[r] = upd ? cn : c_reg[r];
            h_reg[r] = upd ? hn : h_reg[r];
            const int off = (row0 + kgrp * 4 + r) * 512 + ohid;
            const u16 hb = f2bf(h_reg[r]);
            const u16 lb = f2bf(h_reg[r] - bf2f(hb));
            __hip_atomic_store(wr + off, ((unsigned)lb << 16) | (unsigned)hb,
                               __ATOMIC_RELAXED, __HIP_MEMORY_SCOPE_AGENT);
        }

        // ---- per-BLOCK publish: drain each wave's stores, converge, ONE relaxed add ----
        asm volatile("s_waitcnt vmcnt(0)" ::: "memory");
        __syncthreads();
        if (tid == 0)
            __hip_atomic_fetch_add(myctr, 1u, __ATOMIC_RELAXED, __HIP_MEMORY_SCOPE_AGENT);
        asm volatile("" ::: "memory");
    }
}

// ---- qt[256][512] = q_h @ M (MFMA, h from packed plane, M hi+lo, 4 products) ----
__global__ __launch_bounds__(256) void qt_kernel(
        const unsigned* __restrict__ hpk,
        const u16* __restrict__ Mt_hi, const u16* __restrict__ Mt_lo, float* __restrict__ qt)
{
    const int tid = threadIdx.x, lane = tid & 63, w = tid >> 6;
    const int wr = w >> 1, wc = w & 1;
    const int row0 = blockIdx.x * 32 + wr * 16;
    const int col0 = blockIdx.y * 32 + wc * 16;
    const int frow = lane & 15, kgrp = lane >> 4;
    f32x4 acc = {0, 0, 0, 0};
    const unsigned* ap = hpk + (row0 + frow) * 512 + kgrp * 8;
    const u16* bph = Mt_hi + (col0 + frow) * 512 + kgrp * 8;
    const u16* bpl = Mt_lo + (col0 + frow) * 512 + kgrp * 8;
    #pragma unroll 4
    for (int ks = 0; ks < 16; ++ks) {
        const u32x4 a0 = *(const u32x4*)(ap + ks * 32);
        const u32x4 a1 = *(const u32x4*)(ap + ks * 32 + 4);
        s16x8 ah, al;
        #pragma unroll
        for (int i = 0; i < 4; ++i) {
            ah[i]     = (short)(u16)a0[i];
            al[i]     = (short)(u16)(a0[i] >> 16);
            ah[4 + i] = (short)(u16)a1[i];
            al[4 + i] = (short)(u16)(a1[i] >> 16);
        }
        const s16x8 bh = *(const s16x8*)(bph + ks * 32);
        const s16x8 bl = *(const s16x8*)(bpl + ks * 32);
        acc = MFMA(ah, bh, acc);
        acc = MFMA(al, bh, acc);
        acc = MFMA(ah, bl, acc);
        acc = MFMA(al, bl, acc);
    }
    #pragma unroll
    for (int r = 0; r < 4; ++r)
        qt[(row0 + kgrp * 4 + r) * 512 + col0 + frow] = acc[r];
}

// ---- final MLP: 1280 rows, one wave per row ----
__global__ __launch_bounds__(256) void dense_out(const float* __restrict__ qt,
        const unsigned* __restrict__ hpk,
        const float* __restrict__ W1, const float* __restrict__ b1,
        const float* __restrict__ W2, const float* __restrict__ b2, float* __restrict__ out)
{
    const int r    = blockIdx.x * 4 + (threadIdx.x >> 6);
    const int lane = threadIdx.x & 63;
    int qi, ri;
    if (r < 256) { qi = r; ri = r; }
    else { const int g = (r - 256) >> 8; const int b = (r - 256) & 255; qi = b; ri = (b + g + 1) & 255; }

    float p[10];
    #pragma unroll
    for (int u = 0; u < 10; ++u) p[u] = 0.0f;
    for (int k = lane; k < 512; k += 64) {
        const float xq = qt[qi * 512 + k];
        #pragma unroll
        for (int u = 0; u < 10; ++u) p[u] += xq * W1[k * 10 + u];
    }
    for (int k = lane; k < 512; k += 64) {
        const unsigned v = hpk[(256 + ri) * 512 + k];
        const float xr = bf2f((u16)v) + bf2f((u16)(v >> 16));
        #pragma unroll
        for (int u = 0; u < 10; ++u) p[u] += xr * W1[(512 + k) * 10 + u];
    }
    #pragma unroll
    for (int off = 32; off; off >>= 1) {
        #pragma unroll
        for (int u = 0; u < 10; ++u) p[u] += __shfl_xor(p[u], off);
    }
    float s = b2[0];
    #pragma unroll
    for (int u = 0; u < 10; ++u) {
        const float h1 = fmaxf(p[u] + b1[u], 0.0f);
        s += h1 * W2[u];
    }
    if (lane == 0) out[r] = fmaxf(s, 0.0f);
}

extern "C" void kernel_launch(void* const* d_in, const int* in_sizes, int n_in,
                              void* d_out, int out_size, void* d_ws, size_t ws_size,
                              hipStream_t stream)
{
    const float* emb  = (const float*)d_in[0];
    const float* Wk   = (const float*)d_in[1];
    const float* bias = (const float*)d_in[2];
    const float* wi   = (const float*)d_in[3];
    const float* wf   = (const float*)d_in[4];
    const float* wo   = (const float*)d_in[5];
    const float* M    = (const float*)d_in[6];
    const float* W1   = (const float*)d_in[7];
    const float* b1   = (const float*)d_in[8];
    const float* W2   = (const float*)d_in[9];
    const float* b2   = (const float*)d_in[10];
    const int*   qtok = (const int*)d_in[11];
    const int*   rtok = (const int*)d_in[12];
    const int*   qlen = (const int*)d_in[13];
    const int*   rlen = (const int*)d_in[14];
    float* out = (float*)d_out;

    // workspace layout (16B-aligned); total ~10.5 MB
    char* ws = (char*)d_ws;
    u16*      Wt_hi = (u16*)(ws + 0);            // 3,145,728
    u16*      Wt_lo = (u16*)(ws + 3145728);      // 3,145,728
    u16*      Mt_hi = (u16*)(ws + 6291456);      //   524,288
    u16*      Mt_lo = (u16*)(ws + 6815744);      //   524,288
    unsigned* h0p   = (unsigned*)(ws + 7340032); // 1,048,576 (packed lo|hi)
    unsigned* h1p   = (unsigned*)(ws + 8388608); // 1,048,576
    float*    qt    = (float*)(ws + 9437184);    //   524,288
    unsigned* ctr   = (unsigned*)(ws + 9961472); // 8 counters @ 128B stride

    transpose_split<<<dim3(64, 24), dim3(32, 8), 0, stream>>>(Wk, Wt_hi, Wt_lo, 768, 2048);
    transpose_split<<<dim3(16, 16), dim3(32, 8), 0, stream>>>(M, Mt_hi, Mt_lo, 512, 512);
    zero_state<<<1024, 256, 0, stream>>>(h0p, ctr);

    // 128 KiB dynamic LDS (mechanism proven rounds 11/12/20)
    hipFuncSetAttribute((const void*)lstm_persist,
                        hipFuncAttributeMaxDynamicSharedMemorySize, 131072);
    lstm_persist<<<256, 256, 131072, stream>>>(emb, qtok, rtok, qlen, rlen,
                                               Wt_hi, Wt_lo, bias, wi, wf, wo,
                                               h0p, h1p, ctr);

    // 128 steps (even) => final h lives in h0p
    qt_kernel<<<dim3(8, 16), 256, 0, stream>>>(h0p, Mt_hi, Mt_lo, qt);
    dense_out<<<320, 256, 0, stream>>>(qt, h0p, W1, b1, W2, b2, out);
}

// Round 22
// 1812.178 us; speedup vs baseline: 2.6016x; 1.0209x over previous
//
#include <hip/hip_runtime.h>

// DualEncoderLSTMDense: dual peephole-LSTM encoders (shared weights) + M-projection + tiny MLP.
// B=256, L=128, E=256, H=512, VOCAB=90000, NUM_NEG=4, forget_bias=2.0.
//
// Round 22: R20 base (best per-dispatch: ~2000us; h-part W_hi+W_lo in LDS, per-WAVE
// publish — R21's per-block publish was neutral-to-negative, reverted) + x-part W_hi
// staged into the FINAL 32KB of LDS (total 160KB = full CU budget; AITER fmha precedent).
// Only x W_lo (32KB/block/step) still streams from L2, consumed by the last product in
// the x chain where latency hides best. Values/order untouched -> bit-identical
// (absmax 1.953125e-3). Failure mode: 160KB launch rejected -> stub zeros -> revert.

typedef unsigned short u16;
typedef unsigned long long u64;
typedef __attribute__((ext_vector_type(8))) short    s16x8;
typedef __attribute__((ext_vector_type(4))) float    f32x4;
typedef __attribute__((ext_vector_type(4))) unsigned u32x4;

#define MFMA(a, b, c) __builtin_amdgcn_mfma_f32_16x16x32_bf16((a), (b), (c), 0, 0, 0)

__device__ __forceinline__ u16 f2bf(float f) {
    union { float f; unsigned u; } v; v.f = f;
    unsigned r = v.u + 0x7FFFu + ((v.u >> 16) & 1u);
    return (u16)(r >> 16);
}
__device__ __forceinline__ float bf2f(u16 h) {
    union { unsigned u; float f; } v; v.u = ((unsigned)h) << 16;
    return v.f;
}
__device__ __forceinline__ float sigm(float x) { return 1.0f / (1.0f + expf(-x)); }

// ---- transpose fp32 [R][C] -> bf16 hi/lo planes [C][R] ----
__global__ __launch_bounds__(256) void transpose_split(const float* __restrict__ src,
        u16* __restrict__ dhi, u16* __restrict__ dlo, int R, int C)
{
    __shared__ float tile[32][33];
    const int bx = blockIdx.x * 32;
    const int by = blockIdx.y * 32;
    for (int i = threadIdx.y; i < 32; i += 8)
        tile[i][threadIdx.x] = src[(size_t)(by + i) * C + bx + threadIdx.x];
    __syncthreads();
    for (int i = threadIdx.y; i < 32; i += 8) {
        float v = tile[threadIdx.x][i];
        u16 hi = f2bf(v);
        size_t o = (size_t)(bx + i) * R + by + threadIdx.x;
        dhi[o] = hi;
        dlo[o] = f2bf(v - bf2f(hi));
    }
}

__global__ __launch_bounds__(256) void zero_state(unsigned* __restrict__ h0p,
        unsigned* __restrict__ ctr)
{
    const int i = blockIdx.x * 256 + threadIdx.x;   // grid 1024*256 = 262144
    h0p[i] = 0;
    if (i < 8) ctr[i * 32] = 0;
}

// ---- persistent LSTM: all 128 steps, both encoders (512 batch rows) ----
// 256 blocks (1/CU): rowTile = bid&7 (64 batch rows), hidTile = bid>>3 (16 hid cols).
// Dynamic LDS 160 KiB: [0,64K) W_hi h-part, [64K,128K) W_lo h-part, [128K,160K) W_hi x-part.
__global__ __launch_bounds__(256, 1) void lstm_persist(
        const float* __restrict__ emb, const int* __restrict__ qtok, const int* __restrict__ rtok,
        const int* __restrict__ qlen, const int* __restrict__ rlen,
        const u16* __restrict__ Wt_hi, const u16* __restrict__ Wt_lo,   // [2048][768]
        const float* __restrict__ bias, const float* __restrict__ wi,
        const float* __restrict__ wf, const float* __restrict__ wo,
        unsigned* __restrict__ h0p, unsigned* __restrict__ h1p,         // packed h planes
        unsigned* __restrict__ ctr)
{
    extern __shared__ char smem[];
    u16* whi_h = (u16*)smem;              // 64 KiB (h-part W_hi)
    u16* wlo_h = (u16*)(smem + 65536);    // 64 KiB (h-part W_lo)
    u16* whi_x = (u16*)(smem + 131072);   // 32 KiB (x-part W_hi)

    const int tid = threadIdx.x, lane = tid & 63, w = tid >> 6;
    const int bid = blockIdx.x;
    const int rowTile = bid & 7, hidTile = bid >> 3;
    const int row0 = rowTile * 64 + w * 16, hid0 = hidTile * 16;
    const int frow = lane & 15, kgrp = lane >> 4;
    const int sw = (frow & 7) << 4;

    // ---- stage h-part W_hi+W_lo (64 rows x 64 chunks) and x-part W_hi (64 rows x 32 chunks) ----
    for (int i = tid; i < 4096; i += 256) {
        const int gc = i >> 6, c16 = i & 63;
        const int g = gc >> 4, cc = gc & 15;
        const size_t srcoff = (size_t)(g * 512 + hid0 + cc) * 768 + 256 + c16 * 8;
        const int dst = (gc * 1024 + c16 * 16) ^ ((gc & 7) << 4);
        *(s16x8*)((char*)whi_h + dst) = *(const s16x8*)(Wt_hi + srcoff);
        *(s16x8*)((char*)wlo_h + dst) = *(const s16x8*)(Wt_lo + srcoff);
    }
    for (int i = tid; i < 2048; i += 256) {
        const int gc = i >> 5, c16 = i & 31;
        const int g = gc >> 4, cc = gc & 15;
        const s16x8 v = *(const s16x8*)(Wt_hi + (size_t)(g * 512 + hid0 + cc) * 768 + c16 * 8);
        *(s16x8*)((char*)whi_x + ((gc * 512 + c16 * 16) ^ ((gc & 7) << 4))) = v;
    }

    const int   ohid = hid0 + frow;
    const float bi  = bias[ohid];
    const float bj  = bias[512 + ohid];
    const float bff = bias[1024 + ohid];
    const float bo  = bias[1536 + ohid];
    const float wiv = wi[ohid], wfv = wf[ohid], wov = wo[ohid];
    const int   arow = row0 + frow;
    const int*  tokp = (arow < 256) ? (qtok + arow * 128) : (rtok + (arow - 256) * 128);
    const u16*  wlo_base[4];
    #pragma unroll
    for (int g = 0; g < 4; ++g)
        wlo_base[g] = Wt_lo + (size_t)(g * 512 + hid0 + frow) * 768;
    int lenv[4];
    #pragma unroll
    for (int r = 0; r < 4; ++r) {
        const int rr = row0 + kgrp * 4 + r;
        lenv[r] = (rr < 256) ? qlen[rr] : rlen[rr - 256];
    }
    float c_reg[4] = {0, 0, 0, 0}, h_reg[4] = {0, 0, 0, 0};

    __syncthreads();   // LDS W staged

    unsigned* myctr = ctr + rowTile * 32;

    for (int t = 0; t < 128; ++t) {
        const unsigned* rd = (t & 1) ? h1p : h0p;
        unsigned*       wr = (t & 1) ? h0p : h1p;

        // ---- x-part (token-dependent only; overlaps barrier stragglers) ----
        const int    tok  = tokp[t];
        const float* xrow = emb + (size_t)tok * 256 + kgrp * 8;
        f32x4 fv[16];
        #pragma unroll
        for (int i = 0; i < 16; ++i)
            fv[i] = *(const f32x4*)(xrow + (i >> 1) * 32 + (i & 1) * 4);

        f32x4 acc[4] = {{0,0,0,0},{0,0,0,0},{0,0,0,0},{0,0,0,0}};

        // x-part, K 0..255: split fp32 gather into 2 planes; bh from LDS, bl streamed (L2)
        #pragma unroll
        for (int ks = 0; ks < 8; ++ks) {
            const f32x4 v0 = fv[2 * ks], v1 = fv[2 * ks + 1];
            const float vv[8] = {v0[0], v0[1], v0[2], v0[3], v1[0], v1[1], v1[2], v1[3]};
            s16x8 xh, xl;
            #pragma unroll
            for (int e = 0; e < 8; ++e) {
                const u16 hb = f2bf(vv[e]);
                xh[e] = (short)hb;
                xl[e] = (short)f2bf(vv[e] - bf2f(hb));
            }
            const int kk = ks * 32 + kgrp * 8;
            #pragma unroll
            for (int g = 0; g < 4; ++g) {
                const int gr = g * 16 + frow;
                const s16x8 bh = *(const s16x8*)((const char*)whi_x + ((gr * 512 + kk * 2) ^ sw));
                const s16x8 bl = *(const s16x8*)(wlo_base[g] + kk);
                acc[g] = MFMA(xh, bh, acc[g]);
                acc[g] = MFMA(xl, bh, acc[g]);
                acc[g] = MFMA(xh, bl, acc[g]);
            }
        }

        // ---- wave-autonomous wait: 128 publishes (32 blocks x 4 waves) per step ----
        if (lane == 0) {
            const unsigned target = 128u * (unsigned)t;
            while (__hip_atomic_load(myctr, __ATOMIC_RELAXED, __HIP_MEMORY_SCOPE_AGENT) < target)
                __builtin_amdgcn_s_sleep(2);
        }
        asm volatile("" ::: "memory");

        const unsigned* hrd = rd + arow * 512 + kgrp * 8;

        // ---- h-part, K 256..767, in 2 halves of 8 ks: batched relaxed atomic loads;
        //      bh AND bl from LDS (swizzled ds_read_b128). ----
        #pragma unroll
        for (int half = 0; half < 2; ++half) {
            u64 hv[32];
            #pragma unroll
            for (int i = 0; i < 32; ++i) {
                const int ks = half * 8 + (i >> 2);
                hv[i] = __hip_atomic_load((const u64*)(hrd + ks * 32 + (i & 3) * 2),
                                          __ATOMIC_RELAXED, __HIP_MEMORY_SCOPE_AGENT);
            }
            __builtin_amdgcn_sched_barrier(0);   // keep loads batched ahead of consumption
            #pragma unroll
            for (int j = 0; j < 8; ++j) {
                const int ks = half * 8 + j;
                const int kh = ks * 32;
                s16x8 ah, al;
                #pragma unroll
                for (int i = 0; i < 4; ++i) {
                    const u64 v = hv[j * 4 + i];
                    const unsigned w0 = (unsigned)v, w1 = (unsigned)(v >> 32);
                    ah[2 * i]     = (short)(u16)w0;
                    al[2 * i]     = (short)(u16)(w0 >> 16);
                    ah[2 * i + 1] = (short)(u16)w1;
                    al[2 * i + 1] = (short)(u16)(w1 >> 16);
                }
                #pragma unroll
                for (int g = 0; g < 4; ++g) {
                    const int gr = g * 16 + frow;
                    const int wo_ = (gr * 1024 + (kh + kgrp * 8) * 2) ^ sw;
                    const s16x8 bh = *(const s16x8*)((const char*)whi_h + wo_);
                    const s16x8 bl = *(const s16x8*)((const char*)wlo_h + wo_);
                    acc[g] = MFMA(ah, bh, acc[g]);
                    acc[g] = MFMA(al, bh, acc[g]);
                    acc[g] = MFMA(ah, bl, acc[g]);
                    acc[g] = MFMA(al, bl, acc[g]);
                }
            }
        }

        // ---- gates + peepholes + masking; publish h packed via sc1 atomic store ----
        #pragma unroll
        for (int r = 0; r < 4; ++r) {
            const float cold = c_reg[r];
            const float ig = sigm(acc[0][r] + bi + wiv * cold);
            const float jg = tanhf(acc[1][r] + bj);
            const float fg = sigm(acc[2][r] + bff + wfv * cold + 2.0f);
            const float cn = fg * cold + ig * jg;
            const float og = sigm(acc[3][r] + bo + wov * cn);
            const float hn = og * tanhf(cn);
            const bool upd = (t < lenv[r]);
            c_reg[r] = upd ? cn : c_reg[r];
            h_reg[r] = upd ? hn : h_reg[r];
            const int off = (row0 + kgrp * 4 + r) * 512 + ohid;
            const u16 hb = f2bf(h_reg[r]);
            const u16 lb = f2bf(h_reg[r] - bf2f(hb));
            __hip_atomic_store(wr + off, ((unsigned)lb << 16) | (unsigned)hb,
                               __ATOMIC_RELAXED, __HIP_MEMORY_SCOPE_AGENT);
        }

        // ---- per-wave publish: drain this wave's stores, one relaxed add ----
        asm volatile("s_waitcnt vmcnt(0)" ::: "memory");
        if (lane == 0)
            __hip_atomic_fetch_add(myctr, 1u, __ATOMIC_RELAXED, __HIP_MEMORY_SCOPE_AGENT);
        asm volatile("" ::: "memory");
    }
}

// ---- qt[256][512] = q_h @ M (MFMA, h from packed plane, M hi+lo, 4 products) ----
__global__ __launch_bounds__(256) void qt_kernel(
        const unsigned* __restrict__ hpk,
        const u16* __restrict__ Mt_hi, const u16* __restrict__ Mt_lo, float* __restrict__ qt)
{
    const int tid = threadIdx.x, lane = tid & 63, w = tid >> 6;
    const int wr = w >> 1, wc = w & 1;
    const int row0 = blockIdx.x * 32 + wr * 16;
    const int col0 = blockIdx.y * 32 + wc * 16;
    const int frow = lane & 15, kgrp = lane >> 4;
    f32x4 acc = {0, 0, 0, 0};
    const unsigned* ap = hpk + (row0 + frow) * 512 + kgrp * 8;
    const u16* bph = Mt_hi + (col0 + frow) * 512 + kgrp * 8;
    const u16* bpl = Mt_lo + (col0 + frow) * 512 + kgrp * 8;
    #pragma unroll 4
    for (int ks = 0; ks < 16; ++ks) {
        const u32x4 a0 = *(const u32x4*)(ap + ks * 32);
        const u32x4 a1 = *(const u32x4*)(ap + ks * 32 + 4);
        s16x8 ah, al;
        #pragma unroll
        for (int i = 0; i < 4; ++i) {
            ah[i]     = (short)(u16)a0[i];
            al[i]     = (short)(u16)(a0[i] >> 16);
            ah[4 + i] = (short)(u16)a1[i];
            al[4 + i] = (short)(u16)(a1[i] >> 16);
        }
        const s16x8 bh = *(const s16x8*)(bph + ks * 32);
        const s16x8 bl = *(const s16x8*)(bpl + ks * 32);
        acc = MFMA(ah, bh, acc);
        acc = MFMA(al, bh, acc);
        acc = MFMA(ah, bl, acc);
        acc = MFMA(al, bl, acc);
    }
    #pragma unroll
    for (int r = 0; r < 4; ++r)
        qt[(row0 + kgrp * 4 + r) * 512 + col0 + frow] = acc[r];
}

// ---- final MLP: 1280 rows, one wave per row ----
__global__ __launch_bounds__(256) void dense_out(const float* __restrict__ qt,
        const unsigned* __restrict__ hpk,
        const float* __restrict__ W1, const float* __restrict__ b1,
        const float* __restrict__ W2, const float* __restrict__ b2, float* __restrict__ out)
{
    const int r    = blockIdx.x * 4 + (threadIdx.x >> 6);
    const int lane = threadIdx.x & 63;
    int qi, ri;
    if (r < 256) { qi = r; ri = r; }
    else { const int g = (r - 256) >> 8; const int b = (r - 256) & 255; qi = b; ri = (b + g + 1) & 255; }

    float p[10];
    #pragma unroll
    for (int u = 0; u < 10; ++u) p[u] = 0.0f;
    for (int k = lane; k < 512; k += 64) {
        const float xq = qt[qi * 512 + k];
        #pragma unroll
        for (int u = 0; u < 10; ++u) p[u] += xq * W1[k * 10 + u];
    }
    for (int k = lane; k < 512; k += 64) {
        const unsigned v = hpk[(256 + ri) * 512 + k];
        const float xr = bf2f((u16)v) + bf2f((u16)(v >> 16));
        #pragma unroll
        for (int u = 0; u < 10; ++u) p[u] += xr * W1[(512 + k) * 10 + u];
    }
    #pragma unroll
    for (int off = 32; off; off >>= 1) {
        #pragma unroll
        for (int u = 0; u < 10; ++u) p[u] += __shfl_xor(p[u], off);
    }
    float s = b2[0];
    #pragma unroll
    for (int u = 0; u < 10; ++u) {
        const float h1 = fmaxf(p[u] + b1[u], 0.0f);
        s += h1 * W2[u];
    }
    if (lane == 0) out[r] = fmaxf(s, 0.0f);
}

extern "C" void kernel_launch(void* const* d_in, const int* in_sizes, int n_in,
                              void* d_out, int out_size, void* d_ws, size_t ws_size,
                              hipStream_t stream)
{
    const float* emb  = (const float*)d_in[0];
    const float* Wk   = (const float*)d_in[1];
    const float* bias = (const float*)d_in[2];
    const float* wi   = (const float*)d_in[3];
    const float* wf   = (const float*)d_in[4];
    const float* wo   = (const float*)d_in[5];
    const float* M    = (const float*)d_in[6];
    const float* W1   = (const float*)d_in[7];
    const float* b1   = (const float*)d_in[8];
    const float* W2   = (const float*)d_in[9];
    const float* b2   = (const float*)d_in[10];
    const int*   qtok = (const int*)d_in[11];
    const int*   rtok = (const int*)d_in[12];
    const int*   qlen = (const int*)d_in[13];
    const int*   rlen = (const int*)d_in[14];
    float* out = (float*)d_out;

    // workspace layout (16B-aligned); total ~10.5 MB
    char* ws = (char*)d_ws;
    u16*      Wt_hi = (u16*)(ws + 0);            // 3,145,728
    u16*      Wt_lo = (u16*)(ws + 3145728);      // 3,145,728
    u16*      Mt_hi = (u16*)(ws + 6291456);      //   524,288
    u16*      Mt_lo = (u16*)(ws + 6815744);      //   524,288
    unsigned* h0p   = (unsigned*)(ws + 7340032); // 1,048,576 (packed lo|hi)
    unsigned* h1p   = (unsigned*)(ws + 8388608); // 1,048,576
    float*    qt    = (float*)(ws + 9437184);    //   524,288
    unsigned* ctr   = (unsigned*)(ws + 9961472); // 8 counters @ 128B stride

    transpose_split<<<dim3(64, 24), dim3(32, 8), 0, stream>>>(Wk, Wt_hi, Wt_lo, 768, 2048);
    transpose_split<<<dim3(16, 16), dim3(32, 8), 0, stream>>>(M, Mt_hi, Mt_lo, 512, 512);
    zero_state<<<1024, 256, 0, stream>>>(h0p, ctr);

    // 160 KiB dynamic LDS (full CU budget; 128KB mechanism proven R11/12/20; AITER
    // fmha precedent for 160KB workgroups)
    hipFuncSetAttribute((const void*)lstm_persist,
                        hipFuncAttributeMaxDynamicSharedMemorySize, 163840);
    lstm_persist<<<256, 256, 163840, stream>>>(emb, qtok, rtok, qlen, rlen,
                                               Wt_hi, Wt_lo, bias, wi, wf, wo,
                                               h0p, h1p, ctr);

    // 128 steps (even) => final h lives in h0p
    qt_kernel<<<dim3(8, 16), 256, 0, stream>>>(h0p, Mt_hi, Mt_lo, qt);
    dense_out<<<320, 256, 0, stream>>>(qt, h0p, W1, b1, W2, b2, out);
}